// Round 5
// baseline (120.284 us; speedup 1.0000x reference)
//
#include <hip/hip_runtime.h>

#define KS   15
#define PAD  7
#define TILE 64
#define HI   (TILE + KS - 1)   // 78 rows in LDS
#define LDW  84                // LDS row stride (floats)
#define NQ   20                // float4s per loaded row (80-float window [tx-8, tx+72))
#define NIT  (HI * NQ)         // 1560 quad-items per tile
#define STR2 68                // output-staging stride

typedef float f32x4 __attribute__((ext_vector_type(4)));

__global__ __launch_bounds__(256, 6) void dcp_kernel(
    const float* __restrict__ img, const float* __restrict__ weight,
    float* __restrict__ out)
{
    __shared__ float S[HI * LDW];   // 26208 B -> 6 blocks/CU

    const int tid  = threadIdx.x;
    const int wave = tid >> 6;
    const int lane = tid & 63;

    // 2048 blocks, 2 x-adjacent tiles each. XCD-chunked: each XCD owns 2 images.
    const int bid  = blockIdx.x;
    const int swzL = (bid & 7) * 256 + (bid >> 3);
    const int L0   = swzL * 2;                 // even -> pair shares b, ty0

    const int H = 1024, W = 1024;
    const long long plane = (long long)H * W;

    const int b   = L0 >> 8;
    const int ty0 = ((L0 >> 4) & 15) * TILE;
    const int tx0 = (L0 & 15) * TILE;
    const int tx1 = tx0 + TILE;
    const float* base = img + (long long)b * 3 * plane;
    const float scale = weight[0] * (1.0f / (KS * KS));

    auto load3 = [&](int tx, int it, float4* c) {
        int r  = it / NQ;
        int c4 = it - r * NQ;
        int gy = ty0 + r - PAD;
        int gx = tx - 8 + 4 * c4;              // quad-aligned, never straddles edge
        if ((unsigned)gy < (unsigned)H && (unsigned)gx <= (unsigned)(W - 4)) {
            long long off = (long long)gy * W + gx;
            c[0] = *(const float4*)(base + off);
            c[1] = *(const float4*)(base + off + plane);
            c[2] = *(const float4*)(base + off + 2 * plane);
        } else {
            c[0] = c[1] = c[2] = make_float4(0.f, 0.f, 0.f, 0.f);
        }
    };
    auto min3 = [](const float4* c) -> float4 {
        float4 v;
        v.x = fminf(c[0].x, fminf(c[1].x, c[2].x));
        v.y = fminf(c[0].y, fminf(c[1].y, c[2].y));
        v.z = fminf(c[0].z, fminf(c[1].z, c[2].z));
        v.w = fminf(c[0].w, fminf(c[1].w, c[2].w));
        return v;
    };
    auto dswrite = [&](int it, float4 v) {
        int r  = it / NQ;
        int c4 = it - r * NQ;
        *(float4*)(&S[r * LDW + 4 * c4]) = v;
    };

    float buf[32] __attribute__((aligned(16)));

    // ---- phase lambdas (operate on whichever tile's dark data is in S) ----
    auto p2a = [&]() {   // vertical sliding sums, cols 0..63 (lane = col)
        const int rb = wave * 16;
        #pragma unroll
        for (int k = 0; k < 30; ++k) buf[k] = S[(rb + k) * LDW + lane];
        __syncthreads();
        float run = 0.f;
        #pragma unroll
        for (int k = 0; k < 14; ++k) run += buf[k];
        #pragma unroll
        for (int j = 0; j < 16; ++j) {
            run += buf[j + 14];
            S[(rb + j) * LDW + lane] = run;
            run -= buf[j];
        }
    };
    auto p2b = [&]() {   // vertical sliding sums, cols 64..79 (lanes 0..15)
        const int rb = wave * 16;
        const int c  = 64 + lane;
        if (lane < 16) {
            #pragma unroll
            for (int k = 0; k < 30; ++k) buf[k] = S[(rb + k) * LDW + c];
        }
        __syncthreads();
        if (lane < 16) {
            float run = 0.f;
            #pragma unroll
            for (int k = 0; k < 14; ++k) run += buf[k];
            #pragma unroll
            for (int j = 0; j < 16; ++j) {
                run += buf[j + 14];
                S[(rb + j) * LDW + c] = run;
                run -= buf[j];
            }
        }
        __syncthreads();
    };
    auto p3 = [&]() {    // horizontal sliding sums + scale -> stage to STR2 region
        const int r  = lane;
        const int s  = wave;
        const int bp = r * LDW + s * 16;
        #pragma unroll
        for (int q = 0; q < 8; ++q)
            *(float4*)(&buf[4 * q]) = *(const float4*)(&S[bp + 4 * q]);
        float o[16];
        float run = 0.f;
        #pragma unroll
        for (int k = 1; k <= 14; ++k) run += buf[k];
        #pragma unroll
        for (int j = 0; j < 16; ++j) {
            run += buf[j + 15];
            o[j] = run * scale;
            run -= buf[j + 1];
        }
        __syncthreads();                       // all vsum reads done
        #pragma unroll
        for (int q = 0; q < 4; ++q)
            *(float4*)(&S[r * STR2 + s * 16 + 4 * q]) =
                make_float4(o[4 * q], o[4 * q + 1], o[4 * q + 2], o[4 * q + 3]);
        __syncthreads();                       // staging visible
    };
    auto p4 = [&](int txx) {                   // coalesced nontemporal copy-out
        float* obase = out + (long long)b * plane + (long long)ty0 * W + txx;
        #pragma unroll
        for (int k = 0; k < 4; ++k) {
            const int qi  = tid + 256 * k;
            const int row = qi >> 4;
            const int qc  = qi & 15;
            f32x4 v = *(const f32x4*)(&S[row * STR2 + 4 * qc]);
            __builtin_nontemporal_store(v, (f32x4*)(obase + (long long)row * W + 4 * qc));
        }
    };

    // ---- tile 0: P1 (pipelined load + min -> LDS) ----
    {
        float4 c0[3], c1[3];
        load3(tx0, tid, c0);
        #pragma unroll
        for (int k = 0; k < 5; ++k) {
            load3(tx0, tid + 256 * (k + 1), c1);
            dswrite(tid + 256 * k, min3(c0));
            c0[0] = c1[0]; c0[1] = c1[1]; c0[2] = c1[2];
        }
        dswrite(tid + 256 * 5, min3(c0));
        if (tid < NIT - 1536) { load3(tx0, 1536 + tid, c0); dswrite(1536 + tid, min3(c0)); }
    }
    __syncthreads();

    // ---- tile 0 compute, with tile 1 loads interleaved between phases ----
    float4 A0[3], A1[3];
    float4 dark[7];
    load3(tx1, tid,        A0);
    load3(tx1, tid + 256,  A1);
    p2a();
    dark[0] = min3(A0); dark[1] = min3(A1);
    load3(tx1, tid + 512,  A0);
    load3(tx1, tid + 768,  A1);
    p2b();
    dark[2] = min3(A0); dark[3] = min3(A1);
    load3(tx1, tid + 1024, A0);
    load3(tx1, tid + 1280, A1);
    p3();
    dark[4] = min3(A0); dark[5] = min3(A1);
    if (tid < 24) load3(tx1, 1536 + tid, A0);
    p4(tx0);
    dark[6] = min3(A0);                        // only used when tid<24
    __syncthreads();                           // all P4 staging reads complete

    // ---- tile 1: commit dark values to LDS, then compute ----
    #pragma unroll
    for (int k = 0; k < 6; ++k) dswrite(tid + 256 * k, dark[k]);
    if (tid < 24) dswrite(1536 + tid, dark[6]);
    __syncthreads();

    p2a();
    p2b();
    p3();
    p4(tx1);
}

extern "C" void kernel_launch(void* const* d_in, const int* in_sizes, int n_in,
                              void* d_out, int out_size, void* d_ws, size_t ws_size,
                              hipStream_t stream) {
    const float* img    = (const float*)d_in[0];
    const float* weight = (const float*)d_in[1];
    float* out = (float*)d_out;

    dim3 grid(2048);     // 2 tiles per block, 4096 logical tiles
    dim3 block(256);
    dcp_kernel<<<grid, block, 0, stream>>>(img, weight, out);
}

// Round 6
// 82.242 us; speedup vs baseline: 1.4626x; 1.4626x over previous
//
#include <hip/hip_runtime.h>

#define KS   15
#define PAD  7
#define TILE 64
#define HI   (TILE + KS - 1)   // 78 rows in LDS
#define LDW  84                // LDS row stride (floats)
#define NQ   20                // float4s per loaded row (80-float window [tx-8, tx+72))
#define NIT  (HI * NQ)         // 1560 quad-items per tile
#define STR2 68                // output-staging stride

typedef float f32x4 __attribute__((ext_vector_type(4)));

__global__ __launch_bounds__(256, 4) void dcp_kernel(
    const float* __restrict__ img, const float* __restrict__ weight,
    float* __restrict__ out)
{
    __shared__ float S[HI * LDW];   // 26208 B

    const int tid  = threadIdx.x;
    const int wave = tid >> 6;
    const int lane = tid & 63;

    // 2048 blocks, 2 x-adjacent tiles each. XCD-chunked: each XCD owns 2 images.
    const int bid  = blockIdx.x;
    const int swzL = (bid & 7) * 256 + (bid >> 3);
    const int L0   = swzL * 2;                 // even -> pair shares b, ty0

    const int H = 1024, W = 1024;
    const long long plane = (long long)H * W;

    const int b   = L0 >> 8;
    const int ty0 = ((L0 >> 4) & 15) * TILE;
    const int tx0 = (L0 & 15) * TILE;
    const int tx1 = tx0 + TILE;
    const float* base = img + (long long)b * 3 * plane;
    const float scale = weight[0] * (1.0f / (KS * KS));

    auto load3 = [&](int tx, int it, float4* c) {
        int r  = it / NQ;
        int c4 = it - r * NQ;
        int gy = ty0 + r - PAD;
        int gx = tx - 8 + 4 * c4;              // quad-aligned, never straddles edge
        if ((unsigned)gy < (unsigned)H && (unsigned)gx <= (unsigned)(W - 4)) {
            long long off = (long long)gy * W + gx;
            c[0] = *(const float4*)(base + off);
            c[1] = *(const float4*)(base + off + plane);
            c[2] = *(const float4*)(base + off + 2 * plane);
        } else {
            c[0] = c[1] = c[2] = make_float4(0.f, 0.f, 0.f, 0.f);
        }
    };
    auto min3 = [](const float4* c) -> float4 {
        float4 v;
        v.x = fminf(c[0].x, fminf(c[1].x, c[2].x));
        v.y = fminf(c[0].y, fminf(c[1].y, c[2].y));
        v.z = fminf(c[0].z, fminf(c[1].z, c[2].z));
        v.w = fminf(c[0].w, fminf(c[1].w, c[2].w));
        return v;
    };
    auto dswrite = [&](int it, float4 v) {
        int r  = it / NQ;
        int c4 = it - r * NQ;
        *(float4*)(&S[r * LDW + 4 * c4]) = v;
    };

    float buf[32] __attribute__((aligned(16)));

    auto p2a = [&]() {   // vertical sliding sums, cols 0..63 (lane = col)
        const int rb = wave * 16;
        #pragma unroll
        for (int k = 0; k < 30; ++k) buf[k] = S[(rb + k) * LDW + lane];
        __syncthreads();
        float run = 0.f;
        #pragma unroll
        for (int k = 0; k < 14; ++k) run += buf[k];
        #pragma unroll
        for (int j = 0; j < 16; ++j) {
            run += buf[j + 14];
            S[(rb + j) * LDW + lane] = run;
            run -= buf[j];
        }
    };
    auto p2b = [&]() {   // vertical sliding sums, cols 64..79 (lanes 0..15)
        const int rb = wave * 16;
        const int c  = 64 + lane;
        if (lane < 16) {
            #pragma unroll
            for (int k = 0; k < 30; ++k) buf[k] = S[(rb + k) * LDW + c];
        }
        __syncthreads();
        if (lane < 16) {
            float run = 0.f;
            #pragma unroll
            for (int k = 0; k < 14; ++k) run += buf[k];
            #pragma unroll
            for (int j = 0; j < 16; ++j) {
                run += buf[j + 14];
                S[(rb + j) * LDW + c] = run;
                run -= buf[j];
            }
        }
        __syncthreads();
    };
    auto p3 = [&]() {    // horizontal sliding sums + scale -> stage at STR2
        const int r  = lane;
        const int s  = wave;
        const int bp = r * LDW + s * 16;
        #pragma unroll
        for (int q = 0; q < 8; ++q)
            *(float4*)(&buf[4 * q]) = *(const float4*)(&S[bp + 4 * q]);
        float o[16];
        float run = 0.f;
        #pragma unroll
        for (int k = 1; k <= 14; ++k) run += buf[k];
        #pragma unroll
        for (int j = 0; j < 16; ++j) {
            run += buf[j + 15];
            o[j] = run * scale;
            run -= buf[j + 1];
        }
        __syncthreads();                       // all vsum reads done
        #pragma unroll
        for (int q = 0; q < 4; ++q)
            *(float4*)(&S[r * STR2 + s * 16 + 4 * q]) =
                make_float4(o[4 * q], o[4 * q + 1], o[4 * q + 2], o[4 * q + 3]);
        __syncthreads();                       // staging visible
    };
    auto p4 = [&](int txx) {                   // coalesced nontemporal copy-out
        float* obase = out + (long long)b * plane + (long long)ty0 * W + txx;
        #pragma unroll
        for (int k = 0; k < 4; ++k) {
            const int qi  = tid + 256 * k;
            const int row = qi >> 4;
            const int qc  = qi & 15;
            f32x4 v = *(const f32x4*)(&S[row * STR2 + 4 * qc]);
            __builtin_nontemporal_store(v, (f32x4*)(obase + (long long)row * W + 4 * qc));
        }
    };

    // ---- tile 0: P1 (pipelined load + min -> LDS) ----
    {
        float4 c0[3], c1[3];
        load3(tx0, tid, c0);
        #pragma unroll
        for (int k = 0; k < 5; ++k) {
            load3(tx0, tid + 256 * (k + 1), c1);
            dswrite(tid + 256 * k, min3(c0));
            c0[0] = c1[0]; c0[1] = c1[1]; c0[2] = c1[2];
        }
        dswrite(tid + 256 * 5, min3(c0));
        if (tid < NIT - 1536) { load3(tx0, 1536 + tid, c0); dswrite(1536 + tid, min3(c0)); }
    }
    __syncthreads();

    // ---- tile 0 compute, tile 1 loads interleaved between phases ----
    float4 A0[3], A1[3], T2[3];
    float4 d0, d1, d2, d3, d4, d5;
    load3(tx1, tid,        A0);
    load3(tx1, tid + 256,  A1);
    p2a();
    d0 = min3(A0); d1 = min3(A1);
    load3(tx1, tid + 512,  A0);
    load3(tx1, tid + 768,  A1);
    p2b();
    d2 = min3(A0); d3 = min3(A1);
    load3(tx1, tid + 1024, A0);
    load3(tx1, tid + 1280, A1);
    if (tid < NIT - 1536) load3(tx1, 1536 + tid, T2);
    p3();
    d4 = min3(A0); d5 = min3(A1);
    // Early commit: items 1280..1559 land in S rows 64..77, which are dead
    // after p2b and disjoint from p4's staging region (floats < 4352).
    dswrite(tid + 1280, d5);
    if (tid < NIT - 1536) dswrite(1536 + tid, min3(T2));
    p4(tx0);
    __syncthreads();                           // staging reads + row64+ writes done

    // ---- tile 1: commit remaining dark rows 0..63, then compute ----
    dswrite(tid,        d0);
    dswrite(tid + 256,  d1);
    dswrite(tid + 512,  d2);
    dswrite(tid + 768,  d3);
    dswrite(tid + 1024, d4);
    __syncthreads();

    p2a();
    p2b();
    p3();
    p4(tx1);
}

extern "C" void kernel_launch(void* const* d_in, const int* in_sizes, int n_in,
                              void* d_out, int out_size, void* d_ws, size_t ws_size,
                              hipStream_t stream) {
    const float* img    = (const float*)d_in[0];
    const float* weight = (const float*)d_in[1];
    float* out = (float*)d_out;

    dim3 grid(2048);     // 2 tiles per block, 4096 logical tiles
    dim3 block(256);
    dcp_kernel<<<grid, block, 0, stream>>>(img, weight, out);
}

// Round 7
// 51.451 us; speedup vs baseline: 2.3378x; 1.5985x over previous
//
#include <hip/hip_runtime.h>

#define KS   15
#define PAD  7
#define TILE 64
#define HI   (TILE + KS - 1)   // 78 rows in LDS
#define LDW  84                // LDS row stride (floats): minimal b128 conflicts
#define NQ   20                // float4s per loaded row (80-float window [tx0-8, tx0+72))
#define NIT  (HI * NQ)         // 1560 quad-items per tile
#define STR2 68                // output-staging stride

typedef float f32x4 __attribute__((ext_vector_type(4)));

__global__ __launch_bounds__(256, 6) void dcp_kernel(
    const float* __restrict__ img, const float* __restrict__ weight,
    float* __restrict__ out)
{
    __shared__ float S[HI * LDW];   // 26208 B -> 6 blocks/CU

    const int tid  = threadIdx.x;
    const int wave = tid >> 6;
    const int lane = tid & 63;

    // XCD-chunked swizzle: each XCD gets 512 contiguous logical tiles (2 images).
    const int bid = blockIdx.x;
    const int swz = (bid & 7) * 512 + (bid >> 3);
    const int b   = swz >> 8;
    const int ty0 = ((swz >> 4) & 15) * TILE;
    const int tx0 = (swz & 15) * TILE;

    const int H = 1024, W = 1024;
    const long long plane = (long long)H * W;
    const float* base = img + (long long)b * 3 * plane;
    const float scale = weight[0] * (1.0f / (KS * KS));

    // ---- Phase 1: dark channel, software-pipelined float4 loads (depth 2) ----
    auto load3 = [&](int it, float4* c) {
        int r  = it / NQ;
        int c4 = it - r * NQ;
        int gy = ty0 + r - PAD;
        int gx = tx0 - 8 + 4 * c4;          // quad-aligned, never straddles edge
        if ((unsigned)gy < (unsigned)H && (unsigned)gx <= (unsigned)(W - 4)) {
            long long off = (long long)gy * W + gx;
            c[0] = *(const float4*)(base + off);
            c[1] = *(const float4*)(base + off + plane);
            c[2] = *(const float4*)(base + off + 2 * plane);
        } else {
            c[0] = c[1] = c[2] = make_float4(0.f, 0.f, 0.f, 0.f);
        }
    };
    auto write_min = [&](int it, const float4* c) {
        int r  = it / NQ;
        int c4 = it - r * NQ;
        float4 v;
        v.x = fminf(c[0].x, fminf(c[1].x, c[2].x));
        v.y = fminf(c[0].y, fminf(c[1].y, c[2].y));
        v.z = fminf(c[0].z, fminf(c[1].z, c[2].z));
        v.w = fminf(c[0].w, fminf(c[1].w, c[2].w));
        *(float4*)(&S[r * LDW + 4 * c4]) = v;
    };

    {
        float4 c0[3], c1[3];
        load3(tid, c0);                      // items 0..1535: 6 rounds, all threads
        #pragma unroll
        for (int k = 0; k < 5; ++k) {
            load3(tid + 256 * (k + 1), c1);  // issue next round's loads first
            write_min(tid + 256 * k, c0);    // then wait + write current
            c0[0] = c1[0]; c0[1] = c1[1]; c0[2] = c1[2];
        }
        write_min(tid + 256 * 5, c0);
        if (tid < NIT - 1536) {              // tail items 1536..1559
            load3(1536 + tid, c0);
            write_min(1536 + tid, c0);
        }
    }
    __syncthreads();

    float buf[32] __attribute__((aligned(16)));

    // ---- Phase 2: vertical 15-tap sliding sums, in place ----
    // Round A: wave = y-segment (16 out rows), lane = column 0..63
    {
        const int rb = wave * 16;
        #pragma unroll
        for (int k = 0; k < 30; ++k) buf[k] = S[(rb + k) * LDW + lane];
        __syncthreads();
        float run = 0.f;
        #pragma unroll
        for (int k = 0; k < 14; ++k) run += buf[k];
        #pragma unroll
        for (int j = 0; j < 16; ++j) {
            run += buf[j + 14];
            S[(rb + j) * LDW + lane] = run;   // cols 0..63
            run -= buf[j];
        }
    }
    // Round B: columns 64..79, lanes 0..15 of each wave (disjoint from A writes)
    {
        const int rb = wave * 16;
        const int c  = 64 + lane;
        if (lane < 16) {
            #pragma unroll
            for (int k = 0; k < 30; ++k) buf[k] = S[(rb + k) * LDW + c];
        }
        __syncthreads();
        if (lane < 16) {
            float run = 0.f;
            #pragma unroll
            for (int k = 0; k < 14; ++k) run += buf[k];
            #pragma unroll
            for (int j = 0; j < 16; ++j) {
                run += buf[j + 14];
                S[(rb + j) * LDW + c] = run;
                run -= buf[j];
            }
        }
        __syncthreads();
    }

    // ---- Phase 3: horizontal 15-tap sliding + scale; stage to LDS ----
    {
        const int r = lane;                    // output row 0..63
        const int s = wave;                    // x-segment of 16
        const int bp = r * LDW + s * 16;       // 16B-aligned
        #pragma unroll
        for (int q = 0; q < 8; ++q)
            *(float4*)(&buf[4 * q]) = *(const float4*)(&S[bp + 4 * q]);
        float o[16];
        float run = 0.f;
        #pragma unroll
        for (int k = 1; k <= 14; ++k) run += buf[k];
        #pragma unroll
        for (int j = 0; j < 16; ++j) {
            run += buf[j + 15];
            o[j] = run * scale;
            run -= buf[j + 1];
        }
        __syncthreads();                       // all P3 S-reads done
        #pragma unroll
        for (int q = 0; q < 4; ++q)
            *(float4*)(&S[r * STR2 + s * 16 + 4 * q]) =
                make_float4(o[4 * q], o[4 * q + 1], o[4 * q + 2], o[4 * q + 3]);
    }
    __syncthreads();

    // ---- Phase 4: coalesced nontemporal copy-out ----
    {
        float* obase = out + (long long)b * plane + (long long)ty0 * W + tx0;
        #pragma unroll
        for (int k = 0; k < 4; ++k) {
            const int qi  = tid + 256 * k;     // 1024 quads total
            const int row = qi >> 4;
            const int qc  = qi & 15;
            f32x4 v = *(const f32x4*)(&S[row * STR2 + 4 * qc]);
            __builtin_nontemporal_store(v, (f32x4*)(obase + (long long)row * W + 4 * qc));
        }
    }
}

extern "C" void kernel_launch(void* const* d_in, const int* in_sizes, int n_in,
                              void* d_out, int out_size, void* d_ws, size_t ws_size,
                              hipStream_t stream) {
    const float* img    = (const float*)d_in[0];
    const float* weight = (const float*)d_in[1];
    float* out = (float*)d_out;

    dim3 grid(4096);     // 16 tiles x * 16 tiles y * 16 batch
    dim3 block(256);
    dcp_kernel<<<grid, block, 0, stream>>>(img, weight, out);
}